// Round 1
// baseline (1078.335 us; speedup 1.0000x reference)
//
#include <hip/hip_runtime.h>
#include <stdint.h>
#include <stddef.h>

#define T_TOK 1024
#define NE    16
#define TOPK  4
#define HID   2048
#define INTER 2048
#define CAP   512          // 2*T*K/E
#define GLIMIT 7.0f
#define GALPHA 1.702f

#define BM  128
#define BK  32
#define LDP 40             // LDS pitch in fp16 elems (80B: 16B-aligned, non-pow2 banks)

typedef __attribute__((ext_vector_type(8))) _Float16 half8;
typedef __attribute__((ext_vector_type(4))) float     f32x4;

// ---------------- gating: softmax + top4 + renormalize ----------------
__global__ __launch_bounds__(256) void gating_kernel(
    const float* __restrict__ logits, int* __restrict__ topki, float* __restrict__ topkw)
{
    int t = blockIdx.x * 256 + threadIdx.x;
    if (t >= T_TOK) return;
    float l[NE];
#pragma unroll
    for (int e = 0; e < NE; e++) l[e] = logits[t * NE + e];
    unsigned used = 0;
    float val[TOPK]; int idx[TOPK];
#pragma unroll
    for (int k = 0; k < TOPK; k++) {
        float bv = -3.4e38f; int bi = 0;
#pragma unroll
        for (int e = 0; e < NE; e++) {
            bool ok = (((used >> e) & 1u) == 0u) && (l[e] > bv);
            bv = ok ? l[e] : bv;
            bi = ok ? e : bi;
        }
        used |= (1u << bi); idx[k] = bi; val[k] = bv;
    }
    // renormalized top-k weights == softmax over the top-k logits
    float m = val[0];
    float s = 0.f, w[TOPK];
#pragma unroll
    for (int k = 0; k < TOPK; k++) { w[k] = expf(val[k] - m); s += w[k]; }
    float inv = 1.0f / s;
#pragma unroll
    for (int k = 0; k < TOPK; k++) { topki[t * TOPK + k] = idx[k]; topkw[t * TOPK + k] = w[k] * inv; }
}

// ---------------- per-token dynamic int8 quant (stored as fp16) ----------------
__global__ __launch_bounds__(256) void quant_x_kernel(
    const float* __restrict__ x, _Float16* __restrict__ xq, float* __restrict__ xs)
{
    int t = blockIdx.x;
    const float* row = x + (size_t)t * HID;
    __shared__ float red[256];
    float amax = 0.f;
    for (int i = threadIdx.x; i < HID; i += 256) amax = fmaxf(amax, fabsf(row[i]));
    red[threadIdx.x] = amax; __syncthreads();
    for (int s = 128; s > 0; s >>= 1) {
        if (threadIdx.x < s) red[threadIdx.x] = fmaxf(red[threadIdx.x], red[threadIdx.x + s]);
        __syncthreads();
    }
    float scale = fmaxf(red[0] / 127.0f, 1e-8f);
    if (threadIdx.x == 0) xs[t] = scale;
    for (int i = threadIdx.x; i < HID; i += 256) {
        float q = rintf(row[i] / scale);
        q = fminf(fmaxf(q, -127.f), 127.f);
        xq[(size_t)t * HID + i] = (_Float16)q;
    }
}

// ---------------- routing: order-exact positions, one wave per expert ----------------
__global__ __launch_bounds__(1024) void routing_kernel(
    const int* __restrict__ topki, const float* __restrict__ topkw,
    int* __restrict__ row_src, float* __restrict__ row_w, int* __restrict__ counts)
{
    int wv = threadIdx.x >> 6;   // expert id
    int lane = threadIdx.x & 63;
    int base = 0;
    for (int r0 = 0; r0 < T_TOK * TOPK; r0 += 64) {
        int r = r0 + lane;
        int e = topki[r];
        unsigned long long mask = __ballot(e == wv);
        int pre = __popcll(mask & ((1ULL << lane) - 1ULL));
        if (e == wv) {
            int pos = base + pre;
            if (pos < CAP) {
                row_src[wv * CAP + pos] = r >> 2;     // source token
                row_w[wv * CAP + pos] = topkw[r];
            }
        }
        base += __popcll(mask);
    }
    if (lane == 0) counts[wv] = (base < CAP) ? base : CAP;
}

// ---------------- GEMM1 (x_q · gate_up) + swiglu, fused ----------------
__global__ __launch_bounds__(256) void gemm1_kernel(
    const _Float16* __restrict__ xq, const float* __restrict__ xs,
    const int* __restrict__ row_src, const int* __restrict__ counts,
    const float* __restrict__ gup, const float* __restrict__ gus,
    const float* __restrict__ gub, const float* __restrict__ smo,
    float* __restrict__ act)
{
    int nt = blockIdx.x;   // 0..31 : 64-wide gate column tile (and matching up tile)
    int mt = blockIdx.y;   // 0..3
    int e  = blockIdx.z;
    int count = counts[e];
    int m0 = mt * BM;
    if (m0 >= count) return;

    __shared__ _Float16 sA[BM * LDP];
    __shared__ _Float16 sB[128 * LDP];   // [0..63]=gate cols, [64..127]=up cols

    int t = threadIdx.x;
    int lane = t & 63, w = t >> 6;
    int n16 = lane & 15, quad = lane >> 4;

    int aM = t >> 1, aHalf = t & 1;
    int agr = m0 + aM;
    const _Float16* aptr = nullptr;
    if (agr < count) aptr = xq + (size_t)row_src[e * CAP + agr] * HID;

    f32x4 acc[2][8];
#pragma unroll
    for (int i = 0; i < 2; i++)
#pragma unroll
        for (int j = 0; j < 8; j++) acc[i][j] = (f32x4)0.0f;

    const float* gbase = gup + (size_t)e * HID * (2 * INTER);

    for (int k0 = 0; k0 < HID; k0 += BK) {
        __syncthreads();
        // stage A: 128 rows x 32 k (fp16), 32B per thread
        {
            int4 v0, v1;
            v0.x = v0.y = v0.z = v0.w = 0; v1 = v0;
            if (aptr) {
                const int4* s4 = (const int4*)(aptr + k0 + aHalf * 16);
                v0 = s4[0]; v1 = s4[1];
            }
            int4* d4 = (int4*)&sA[aM * LDP + aHalf * 16];
            d4[0] = v0; d4[1] = v1;
        }
        // stage B (transposed into [n][k]): gate half + up half
        {
            int n = t & 63;
            int kr = (t >> 6) * 8;
#pragma unroll
            for (int h = 0; h < 2; h++) {
                const float* src = gbase + (size_t)(k0 + kr) * (2 * INTER) + h * INTER + nt * 64 + n;
#pragma unroll
                for (int i = 0; i < 8; i++)
                    sB[(h * 64 + n) * LDP + kr + i] = (_Float16)src[(size_t)i * (2 * INTER)];
            }
        }
        __syncthreads();

        half8 af[2], bfr[8];
#pragma unroll
        for (int mf = 0; mf < 2; mf++)
            af[mf] = *(const half8*)&sA[(w * 32 + mf * 16 + n16) * LDP + quad * 8];
#pragma unroll
        for (int nf = 0; nf < 8; nf++)
            bfr[nf] = *(const half8*)&sB[(nf * 16 + n16) * LDP + quad * 8];
#pragma unroll
        for (int mf = 0; mf < 2; mf++)
#pragma unroll
            for (int nf = 0; nf < 8; nf++)
                acc[mf][nf] = __builtin_amdgcn_mfma_f32_16x16x32_f16(af[mf], bfr[nf], acc[mf][nf], 0, 0, 0);
    }

    // epilogue: dequant + swiglu + smooth, store act rows
    const float* gsc = gus + (size_t)e * (2 * INTER);
    const float* gbi = gub + (size_t)e * (2 * INTER);
    const float* sms = smo + (size_t)e * INTER;
#pragma unroll
    for (int mf = 0; mf < 2; mf++) {
#pragma unroll
        for (int r = 0; r < 4; r++) {
            int gr = m0 + w * 32 + mf * 16 + quad * 4 + r;
            if (gr >= count) continue;
            float srow = xs[row_src[e * CAP + gr]];
            float* arow = act + (size_t)(e * CAP + gr) * INTER;
#pragma unroll
            for (int g = 0; g < 4; g++) {
                int col = nt * 64 + g * 16 + n16;
                float yg = acc[mf][g][r]     * srow * gsc[col]         + gbi[col];
                float yu = acc[mf][g + 4][r] * srow * gsc[INTER + col] + gbi[INTER + col];
                float gate = fminf(yg, GLIMIT);
                float up   = fminf(fmaxf(yu, -GLIMIT), GLIMIT);
                float sig  = 1.0f / (1.0f + expf(-GALPHA * gate));
                arow[col] = gate * sig * (up + 1.0f) * sms[col];
            }
        }
    }
}

// ---------------- per-row dynamic requant of act ----------------
__global__ __launch_bounds__(256) void requant_kernel(
    const float* __restrict__ act, const int* __restrict__ counts,
    _Float16* __restrict__ hq, float* __restrict__ hs)
{
    int b = blockIdx.x;           // e*CAP + c
    int e = b >> 9, c = b & (CAP - 1);
    if (c >= counts[e]) return;
    const float* row = act + (size_t)b * INTER;
    __shared__ float red[256];
    float amax = 0.f;
    for (int i = threadIdx.x; i < INTER; i += 256) amax = fmaxf(amax, fabsf(row[i]));
    red[threadIdx.x] = amax; __syncthreads();
    for (int s = 128; s > 0; s >>= 1) {
        if (threadIdx.x < s) red[threadIdx.x] = fmaxf(red[threadIdx.x], red[threadIdx.x + s]);
        __syncthreads();
    }
    float scale = fmaxf(red[0] / 127.0f, 1e-8f);
    if (threadIdx.x == 0) hs[b] = scale;
    for (int i = threadIdx.x; i < INTER; i += 256) {
        float q = rintf(row[i] / scale);
        q = fminf(fmaxf(q, -127.f), 127.f);
        hq[(size_t)b * INTER + i] = (_Float16)q;
    }
}

// ---------------- GEMM2 (h_q · down) + dequant + weighted combine ----------------
__global__ __launch_bounds__(256) void gemm2_kernel(
    const _Float16* __restrict__ hq, const float* __restrict__ hs,
    const int* __restrict__ row_src, const float* __restrict__ row_w,
    const int* __restrict__ counts, const float* __restrict__ dwn,
    const float* __restrict__ dsc, const float* __restrict__ dbi,
    float* __restrict__ out)
{
    int nt = blockIdx.x;   // 0..15 : 128-wide H tile
    int mt = blockIdx.y;   // 0..3
    int e  = blockIdx.z;
    int count = counts[e];
    int m0 = mt * BM;
    if (m0 >= count) return;

    __shared__ _Float16 sA[BM * LDP];
    __shared__ _Float16 sB[128 * LDP];

    int t = threadIdx.x;
    int lane = t & 63, w = t >> 6;
    int n16 = lane & 15, quad = lane >> 4;

    int aM = t >> 1, aHalf = t & 1;
    int agr = m0 + aM;
    const _Float16* aptr = nullptr;
    if (agr < count) aptr = hq + (size_t)(e * CAP + agr) * INTER;

    f32x4 acc[2][8];
#pragma unroll
    for (int i = 0; i < 2; i++)
#pragma unroll
        for (int j = 0; j < 8; j++) acc[i][j] = (f32x4)0.0f;

    const float* bbase = dwn + (size_t)e * INTER * HID;

    for (int k0 = 0; k0 < INTER; k0 += BK) {
        __syncthreads();
        {
            int4 v0, v1;
            v0.x = v0.y = v0.z = v0.w = 0; v1 = v0;
            if (aptr) {
                const int4* s4 = (const int4*)(aptr + k0 + aHalf * 16);
                v0 = s4[0]; v1 = s4[1];
            }
            int4* d4 = (int4*)&sA[aM * LDP + aHalf * 16];
            d4[0] = v0; d4[1] = v1;
        }
        {
            int n = t & 127;
            int kr = (t >> 7) * 16;
            const float* src = bbase + (size_t)(k0 + kr) * HID + nt * 128 + n;
#pragma unroll
            for (int i = 0; i < 16; i++)
                sB[n * LDP + kr + i] = (_Float16)src[(size_t)i * HID];
        }
        __syncthreads();

        half8 af[2], bfr[8];
#pragma unroll
        for (int mf = 0; mf < 2; mf++)
            af[mf] = *(const half8*)&sA[(w * 32 + mf * 16 + n16) * LDP + quad * 8];
#pragma unroll
        for (int nf = 0; nf < 8; nf++)
            bfr[nf] = *(const half8*)&sB[(nf * 16 + n16) * LDP + quad * 8];
#pragma unroll
        for (int mf = 0; mf < 2; mf++)
#pragma unroll
            for (int nf = 0; nf < 8; nf++)
                acc[mf][nf] = __builtin_amdgcn_mfma_f32_16x16x32_f16(af[mf], bfr[nf], acc[mf][nf], 0, 0, 0);
    }

    const float* dscE = dsc + (size_t)e * HID;
    const float* dbiE = dbi + (size_t)e * HID;
#pragma unroll
    for (int mf = 0; mf < 2; mf++) {
#pragma unroll
        for (int r = 0; r < 4; r++) {
            int gr = m0 + w * 32 + mf * 16 + quad * 4 + r;
            if (gr >= count) continue;
            int ri = e * CAP + gr;
            float hsr = hs[ri];
            float wr  = row_w[ri];
            float* orow = out + (size_t)row_src[ri] * HID;
#pragma unroll
            for (int nf = 0; nf < 8; nf++) {
                int col = nt * 128 + nf * 16 + n16;
                float z = acc[mf][nf][r] * hsr * dscE[col] + dbiE[col];
                atomicAdd(&orow[col], wr * z);
            }
        }
    }
}

// ---------------- launch ----------------
extern "C" void kernel_launch(void* const* d_in, const int* in_sizes, int n_in,
                              void* d_out, int out_size, void* d_ws, size_t ws_size,
                              hipStream_t stream)
{
    (void)in_sizes; (void)n_in; (void)out_size; (void)ws_size;
    const float* x   = (const float*)d_in[0];
    const float* rl  = (const float*)d_in[1];
    const float* gup = (const float*)d_in[2];
    const float* gus = (const float*)d_in[3];
    const float* gub = (const float*)d_in[4];
    const float* smo = (const float*)d_in[5];
    const float* dwn = (const float*)d_in[6];
    const float* dsc = (const float*)d_in[7];
    const float* dbi = (const float*)d_in[8];
    float* out = (float*)d_out;

    char* p = (char*)d_ws;
    auto carve = [&](size_t bytes) -> char* {
        char* r = p; p += (bytes + 255) & ~(size_t)255; return r;
    };
    _Float16* xq   = (_Float16*)carve((size_t)T_TOK * HID * 2);
    float* xs      = (float*)carve((size_t)T_TOK * 4);
    int* topki     = (int*)carve((size_t)T_TOK * TOPK * 4);
    float* topkw   = (float*)carve((size_t)T_TOK * TOPK * 4);
    int* counts    = (int*)carve((size_t)NE * 4);
    int* rsrc      = (int*)carve((size_t)NE * CAP * 4);
    float* rw      = (float*)carve((size_t)NE * CAP * 4);
    float* actb    = (float*)carve((size_t)NE * CAP * INTER * 4);
    _Float16* hq   = (_Float16*)carve((size_t)NE * CAP * INTER * 2);
    float* hsb     = (float*)carve((size_t)NE * CAP * 4);

    hipMemsetAsync(d_out, 0, (size_t)T_TOK * HID * 4, stream);
    gating_kernel<<<dim3((T_TOK + 255) / 256), 256, 0, stream>>>(rl, topki, topkw);
    quant_x_kernel<<<dim3(T_TOK), 256, 0, stream>>>(x, xq, xs);
    routing_kernel<<<dim3(1), 1024, 0, stream>>>(topki, topkw, rsrc, rw, counts);
    gemm1_kernel<<<dim3(INTER / 64, CAP / BM, NE), 256, 0, stream>>>(
        xq, xs, rsrc, counts, gup, gus, gub, smo, actb);
    requant_kernel<<<dim3(NE * CAP), 256, 0, stream>>>(actb, counts, hq, hsb);
    gemm2_kernel<<<dim3(HID / 128, CAP / BM, NE), 256, 0, stream>>>(
        hq, hsb, rsrc, rw, counts, dwn, dsc, dbi, out);
}